// Round 3
// baseline (9732.900 us; speedup 1.0000x reference)
//
#include <hip/hip_runtime.h>
#include <math.h>

#define NB 16
#define NS 4096
#define DIN 512
#define NG 2
#define NC 320
#define GC 640          // NG*NC
#define DG 128          // D_out / G
#define NROW (NB*NS)    // 65536
#define KC 8            // k chunk staged in LDS
#define NIT (DIN/KC)    // 64
#define EPSV 1e-10f

// async global->LDS, 16B per lane; lds dest must be wave-uniform base + lane*16
__device__ __forceinline__ void gload_lds16(const float* g, float* l) {
    __builtin_amdgcn_global_load_lds(
        (const __attribute__((address_space(1))) void*)g,
        (__attribute__((address_space(3))) void*)l,
        16, 0, 0);
}

// W[640][512] -> Wt[512][640]
__global__ void transpose_w(const float* __restrict__ W, float* __restrict__ Wt) {
    int idx = blockIdx.x * 256 + threadIdx.x;
    if (idx >= GC * DIN) return;
    int k = idx / GC, o = idx - k * GC;
    Wt[idx] = W[(size_t)o * DIN + k];
}

// ======================= A: GEMM -> logits (f32, +bias) =======================
#define RTA 64
__global__ __launch_bounds__(512, 6) void gemm_logits(
    const float* __restrict__ X, const float* __restrict__ Wt,
    const float* __restrict__ bias, float* __restrict__ logits)
{
    __shared__ __align__(16) float WtC[2][KC][GC];   // 2 x 20 KB
    __shared__ __align__(16) float AC[2][RTA][KC];   // 2 x 2 KB

    const int t = threadIdx.x;
    const int lane = t & 63;
    const int wid = t >> 6;                          // 0..7
    const int row0 = blockIdx.x * RTA;

    float acc[8][10];
    #pragma unroll
    for (int r = 0; r < 8; ++r)
        #pragma unroll
        for (int j = 0; j < 10; ++j) acc[r][j] = 0.0f;

    auto stage = [&](int b, int k0) {
        const float* gw = Wt + (size_t)k0 * GC;
        #pragma unroll
        for (int i = 0; i < 3; ++i) {                // 20 x 1KB chunks over 8 waves
            int ci = wid + 8 * i;
            if (ci < 20)
                gload_lds16(gw + ci * 256 + 4 * lane, &WtC[b][0][0] + ci * 256);
        }
        if (wid == 4) {                              // X rows 0..31 of this tile
            const float* gx = X + (size_t)(row0 + (lane >> 1)) * DIN + k0 + 4 * (lane & 1);
            gload_lds16(gx, &AC[b][0][0]);
        }
        if (wid == 5) {                              // X rows 32..63
            const float* gx = X + (size_t)(row0 + 32 + (lane >> 1)) * DIN + k0 + 4 * (lane & 1);
            gload_lds16(gx, &AC[b][32][0]);
        }
    };

    stage(0, 0);
    __syncthreads();

    int cur = 0;
    for (int it = 0; it < NIT; ++it) {
        if (it + 1 < NIT) stage(cur ^ 1, (it + 1) * KC);
        #pragma unroll
        for (int kk = 0; kk < KC; ++kk) {
            float w[10];
            #pragma unroll
            for (int j = 0; j < 10; ++j) w[j] = WtC[cur][kk][lane + 64 * j];
            #pragma unroll
            for (int r = 0; r < 8; ++r) {
                float a = AC[cur][wid * 8 + r][kk];
                #pragma unroll
                for (int j = 0; j < 10; ++j) acc[r][j] = fmaf(a, w[j], acc[r][j]);
            }
        }
        __syncthreads();
        cur ^= 1;
    }

    float bv[10];
    #pragma unroll
    for (int j = 0; j < 10; ++j) bv[j] = bias[lane + 64 * j];
    #pragma unroll
    for (int r = 0; r < 8; ++r) {
        const size_t row = row0 + wid * 8 + r;
        #pragma unroll
        for (int j = 0; j < 10; ++j)
            logits[row * GC + lane + 64 * j] = acc[r][j] + bv[j];
    }
}

// ======================= B: epilogue =======================
#define RTB 32
__global__ __launch_bounds__(256, 8) void epilogue(
    const float* __restrict__ logits, const int* __restrict__ vlen,
    const float* __restrict__ U, const float* __restrict__ CB,
    const float* __restrict__ tptr, float* __restrict__ out,
    float* __restrict__ gacc)
{
    __shared__ float uacc[GC];
    const int t = threadIdx.x;
    const int lane = t & 63;
    const int wid = t >> 6;
    const int row0 = blockIdx.x * RTB;

    for (int i = t; i < GC; i += 256) uacc[i] = 0.0f;
    __syncthreads();

    const float T = *tptr;
    const int vl = vlen[row0 >> 12];

    #pragma unroll 2
    for (int r = 0; r < 8; ++r) {
        const int row = row0 + wid * 8 + r;
        const int ss = row & (NS - 1);
        const bool valid = ss < vl;

        float lg[10], z[10];
        #pragma unroll
        for (int j = 0; j < 10; ++j)
            lg[j] = logits[(size_t)row * GC + lane + 64 * j];
        #pragma unroll
        for (int j = 0; j < 10; ++j) {
            float u = U[(size_t)row * GC + lane + 64 * j];
            float gn = -logf(-logf(u + EPSV) + EPSV);
            z[j] = (lg[j] + gn) / T;
        }

        #pragma unroll
        for (int g = 0; g < 2; ++g) {
            const int j0 = g * 5;

            // max + argmax (first-occurrence tie-break)
            float mv = z[j0];
            int mo = lane + 64 * j0;
            #pragma unroll
            for (int j = j0 + 1; j < j0 + 5; ++j) {
                if (z[j] > mv) { mv = z[j]; mo = lane + 64 * j; }
            }
            #pragma unroll
            for (int d = 1; d < 64; d <<= 1) {
                float ov = __shfl_xor(mv, d);
                int   oo = __shfl_xor(mo, d);
                if (ov > mv || (ov == mv && oo < mo)) { mv = ov; mo = oo; }
            }

            // gumbel-softmax denominator
            float se = 0.0f;
            #pragma unroll
            for (int j = j0; j < j0 + 5; ++j) se += expf(z[j] - mv);
            #pragma unroll
            for (int d = 1; d < 64; d <<= 1) se += __shfl_xor(se, d);
            float y = 1.0f / se;
            float q = (1.0f - y) + y;

            // plain softmax for usage
            float m2 = lg[j0];
            #pragma unroll
            for (int j = j0 + 1; j < j0 + 5; ++j) m2 = fmaxf(m2, lg[j]);
            #pragma unroll
            for (int d = 1; d < 64; d <<= 1) m2 = fmaxf(m2, __shfl_xor(m2, d));
            float pe[5];
            float s2 = 0.0f;
            #pragma unroll
            for (int jj = 0; jj < 5; ++jj) {
                pe[jj] = expf(lg[j0 + jj] - m2);
                s2 += pe[jj];
            }
            #pragma unroll
            for (int d = 1; d < 64; d <<= 1) s2 += __shfl_xor(s2, d);
            if (valid) {
                #pragma unroll
                for (int jj = 0; jj < 5; ++jj)
                    atomicAdd(&uacc[lane + 64 * (j0 + jj)], pe[jj] / s2);
            }

            // quantized output
            const int c = mo - g * NC;
            const float2 cv = ((const float2*)(CB + ((size_t)g * NC + c) * DG))[lane];
            float2 ov2;
            ov2.x = q * cv.x;
            ov2.y = q * cv.y;
            ((float2*)(out + (size_t)row * (NG * DG) + g * DG))[lane] = ov2;
        }
    }

    __syncthreads();
    for (int i = t; i < GC; i += 256) atomicAdd(&gacc[i], uacc[i]);
}

__global__ void finalize_usage(const float* __restrict__ gacc,
                               const int* __restrict__ vlen,
                               float* __restrict__ usage_out)
{
    int total = 0;
    #pragma unroll
    for (int b = 0; b < NB; ++b) total += vlen[b];
    int o = threadIdx.x;
    if (o < GC) usage_out[o] = gacc[o] / (float)total;
}

// ======================= fallback: round-1 fused kernel =======================
#define RT 32
__global__ __launch_bounds__(256, 4) void fused_main(
    const float* __restrict__ X, const int* __restrict__ vlen,
    const float* __restrict__ U, const float* __restrict__ Wt,
    const float* __restrict__ bias, const float* __restrict__ CB,
    const float* __restrict__ tptr, float* __restrict__ out,
    float* __restrict__ gacc)
{
    __shared__ __align__(16) float WtC[2][KC][GC];
    __shared__ __align__(16) float AC[2][RT][KC];
    __shared__ float uacc[GC];

    const int t = threadIdx.x;
    const int lane = t & 63;
    const int wid = t >> 6;
    const int row0 = blockIdx.x * RT;

    for (int i = t; i < GC; i += 256) uacc[i] = 0.0f;

    float acc[8][10];
    #pragma unroll
    for (int r = 0; r < 8; ++r)
        #pragma unroll
        for (int j = 0; j < 10; ++j) acc[r][j] = 0.0f;

    auto stage = [&](int b, int k0) {
        const float* gw = Wt + (size_t)k0 * GC;
        #pragma unroll
        for (int i = 0; i < 5; ++i) {
            int base = (wid * 5 + i) * 256;
            gload_lds16(gw + base + 4 * lane, &WtC[b][0][0] + base);
        }
        if (wid == 0) {
            const float* gx = X + (size_t)(row0 + (lane >> 1)) * DIN + k0 + 4 * (lane & 1);
            gload_lds16(gx, &AC[b][0][0]);
        }
    };

    stage(0, 0);
    __syncthreads();

    int cur = 0;
    for (int it = 0; it < NIT; ++it) {
        if (it + 1 < NIT) stage(cur ^ 1, (it + 1) * KC);
        #pragma unroll
        for (int kk = 0; kk < KC; ++kk) {
            float w[10];
            #pragma unroll
            for (int j = 0; j < 10; ++j) w[j] = WtC[cur][kk][lane + 64 * j];
            #pragma unroll
            for (int r = 0; r < 8; ++r) {
                float a = AC[cur][wid * 8 + r][kk];
                #pragma unroll
                for (int j = 0; j < 10; ++j) acc[r][j] = fmaf(a, w[j], acc[r][j]);
            }
        }
        __syncthreads();
        cur ^= 1;
    }

    float bv[10];
    #pragma unroll
    for (int j = 0; j < 10; ++j) bv[j] = bias[lane + 64 * j];
    #pragma unroll
    for (int r = 0; r < 8; ++r)
        #pragma unroll
        for (int j = 0; j < 10; ++j) acc[r][j] += bv[j];

    const float T = *tptr;
    const int vl = vlen[row0 >> 12];

    #pragma unroll 2
    for (int r = 0; r < 8; ++r) {
        const int row = row0 + wid * 8 + r;
        const int ss = row & (NS - 1);
        const bool valid = ss < vl;

        float z[10];
        #pragma unroll
        for (int j = 0; j < 10; ++j) {
            float u = U[(size_t)row * GC + lane + 64 * j];
            float gn = -logf(-logf(u + EPSV) + EPSV);
            z[j] = (acc[r][j] + gn) / T;
        }

        #pragma unroll
        for (int g = 0; g < 2; ++g) {
            const int j0 = g * 5;
            float mv = z[j0];
            int mo = lane + 64 * j0;
            #pragma unroll
            for (int j = j0 + 1; j < j0 + 5; ++j) {
                if (z[j] > mv) { mv = z[j]; mo = lane + 64 * j; }
            }
            #pragma unroll
            for (int d = 1; d < 64; d <<= 1) {
                float ov = __shfl_xor(mv, d);
                int   oo = __shfl_xor(mo, d);
                if (ov > mv || (ov == mv && oo < mo)) { mv = ov; mo = oo; }
            }
            float se = 0.0f;
            #pragma unroll
            for (int j = j0; j < j0 + 5; ++j) se += expf(z[j] - mv);
            #pragma unroll
            for (int d = 1; d < 64; d <<= 1) se += __shfl_xor(se, d);
            float y = 1.0f / se;
            float q = (1.0f - y) + y;

            float m2 = acc[r][j0];
            #pragma unroll
            for (int j = j0 + 1; j < j0 + 5; ++j) m2 = fmaxf(m2, acc[r][j]);
            #pragma unroll
            for (int d = 1; d < 64; d <<= 1) m2 = fmaxf(m2, __shfl_xor(m2, d));
            float pe[5];
            float s2 = 0.0f;
            #pragma unroll
            for (int jj = 0; jj < 5; ++jj) {
                pe[jj] = expf(acc[r][j0 + jj] - m2);
                s2 += pe[jj];
            }
            #pragma unroll
            for (int d = 1; d < 64; d <<= 1) s2 += __shfl_xor(s2, d);
            if (valid) {
                #pragma unroll
                for (int jj = 0; jj < 5; ++jj)
                    atomicAdd(&uacc[lane + 64 * (j0 + jj)], pe[jj] / s2);
            }

            const int c = mo - g * NC;
            const float2 cv = ((const float2*)(CB + ((size_t)g * NC + c) * DG))[lane];
            float2 ov2;
            ov2.x = q * cv.x;
            ov2.y = q * cv.y;
            ((float2*)(out + (size_t)row * (NG * DG) + g * DG))[lane] = ov2;
        }
    }

    __syncthreads();
    for (int i = t; i < GC; i += 256) atomicAdd(&gacc[i], uacc[i]);
}

extern "C" void kernel_launch(void* const* d_in, const int* in_sizes, int n_in,
                              void* d_out, int out_size, void* d_ws, size_t ws_size,
                              hipStream_t stream)
{
    const float* X    = (const float*)d_in[0];
    const int*   vlen = (const int*)d_in[1];
    const float* U    = (const float*)d_in[2];
    const float* W    = (const float*)d_in[3];
    const float* bias = (const float*)d_in[4];
    const float* CB   = (const float*)d_in[5];
    const float* T    = (const float*)d_in[6];
    float* out = (float*)d_out;

    float* Wt   = (float*)d_ws;                        // [0, 327680)
    float* gacc = (float*)d_ws + (size_t)DIN * GC;     // [327680, 328320)
    float* lgts = (float*)d_ws + 328704;               // logits, 41943040 floats
    const size_t need = ((size_t)328704 + (size_t)NROW * GC) * sizeof(float);

    hipMemsetAsync(gacc, 0, GC * sizeof(float), stream);
    transpose_w<<<(GC * DIN + 255) / 256, 256, 0, stream>>>(W, Wt);

    if (ws_size >= need) {
        gemm_logits<<<NROW / RTA, 512, 0, stream>>>(X, Wt, bias, lgts);
        epilogue<<<NROW / RTB, 256, 0, stream>>>(lgts, vlen, U, CB, T, out, gacc);
    } else {
        fused_main<<<NROW / RT, 256, 0, stream>>>(X, vlen, U, Wt, bias, CB, T, out, gacc);
    }
    finalize_usage<<<1, GC, 0, stream>>>(gacc, vlen, out + (size_t)NROW * (NG * DG));
}

// Round 4
// 927.875 us; speedup vs baseline: 10.4895x; 10.4895x over previous
//
#include <hip/hip_runtime.h>
#include <math.h>

#define NB 16
#define NS 4096
#define DIN 512
#define NG 2
#define NC 320
#define GC 640          // NG*NC
#define DG 128          // D_out / G
#define NROW (NB*NS)    // 65536
#define RT 32           // rows per block
#define KC 8            // k chunk staged in LDS
#define NIT (DIN/KC)    // 64
#define EPSV 1e-10f

// async global->LDS, 16B per lane; lds dest is wave-uniform base (+ lane*16 by HW)
__device__ __forceinline__ void gload_lds16(const float* g, float* l) {
    __builtin_amdgcn_global_load_lds(
        (const __attribute__((address_space(1))) void*)g,
        (__attribute__((address_space(3))) void*)l,
        16, 0, 0);
}

// W[640][512] -> Wt[512][640]
__global__ void transpose_w(const float* __restrict__ W, float* __restrict__ Wt) {
    int idx = blockIdx.x * 256 + threadIdx.x;
    if (idx >= GC * DIN) return;
    int k = idx / GC, o = idx - k * GC;
    Wt[idx] = W[(size_t)o * DIN + k];
}

__global__ __launch_bounds__(256, 2) void fused_main(
    const float* __restrict__ X, const int* __restrict__ vlen,
    const float* __restrict__ U, const float* __restrict__ Wt,
    const float* __restrict__ bias, const float* __restrict__ CB,
    const float* __restrict__ tptr, float* __restrict__ out,
    float* __restrict__ gacc)
{
    __shared__ __align__(16) float WtC[2][KC][GC];   // 2 x 20 KB
    __shared__ __align__(16) float AC[2][RT][KC];    // 2 x 1 KB
    __shared__ float uacc[GC];                       // 2.5 KB

    const int t = threadIdx.x;
    const int lane = t & 63;
    const int wid = t >> 6;
    const int row0 = blockIdx.x * RT;

    for (int i = t; i < GC; i += 256) uacc[i] = 0.0f;

    float acc[8][10];
    #pragma unroll
    for (int r = 0; r < 8; ++r)
        #pragma unroll
        for (int j = 0; j < 10; ++j) acc[r][j] = 0.0f;

    auto stage = [&](int b, int k0) {
        const float* gw = Wt + (size_t)k0 * GC;
        #pragma unroll
        for (int i = 0; i < 5; ++i) {               // 5 x 1KB per wave = 20KB
            int base = (wid * 5 + i) * 256;         // flat float offset, wave-uniform
            gload_lds16(gw + base + 4 * lane, &WtC[b][0][0] + base);
        }
        if (wid == 0) {                              // X chunk: 256 floats
            const float* gx = X + (size_t)(row0 + (lane >> 1)) * DIN + k0 + 4 * (lane & 1);
            gload_lds16(gx, &AC[b][0][0]);
        }
    };

    stage(0, 0);
    __syncthreads();

    int cur = 0;
    for (int it = 0; it < NIT; ++it) {
        if (it + 1 < NIT) stage(cur ^ 1, (it + 1) * KC);
        #pragma unroll
        for (int kk = 0; kk < KC; ++kk) {
            float w[10];
            #pragma unroll
            for (int j = 0; j < 10; ++j) w[j] = WtC[cur][kk][lane + 64 * j];
            #pragma unroll
            for (int r = 0; r < 8; ++r) {
                float a = AC[cur][wid * 8 + r][kk];
                #pragma unroll
                for (int j = 0; j < 10; ++j) acc[r][j] = fmaf(a, w[j], acc[r][j]);
            }
        }
        __syncthreads();
        cur ^= 1;
    }

    // bias
    float bv[10];
    #pragma unroll
    for (int j = 0; j < 10; ++j) bv[j] = bias[lane + 64 * j];
    #pragma unroll
    for (int r = 0; r < 8; ++r)
        #pragma unroll
        for (int j = 0; j < 10; ++j) acc[r][j] += bv[j];

    const float T = *tptr;
    const int vl = vlen[row0 >> 12];

    // epilogue — FULLY UNROLLED: every acc index compile-time constant (rule #20)
    #pragma unroll
    for (int r = 0; r < 8; ++r) {
        const int row = row0 + wid * 8 + r;
        const int ss = row & (NS - 1);
        const bool valid = ss < vl;

        float z[10];
        #pragma unroll
        for (int j = 0; j < 10; ++j) {
            float u = U[(size_t)row * GC + lane + 64 * j];
            float gn = -logf(-logf(u + EPSV) + EPSV);
            z[j] = (acc[r][j] + gn) / T;
        }

        #pragma unroll
        for (int g = 0; g < 2; ++g) {
            const int j0 = g * 5;

            // max + argmax (first-occurrence tie-break) over 320 cols
            float mv = z[j0];
            int mo = lane + 64 * j0;
            #pragma unroll
            for (int j = j0 + 1; j < j0 + 5; ++j) {
                if (z[j] > mv) { mv = z[j]; mo = lane + 64 * j; }
            }
            #pragma unroll
            for (int d = 1; d < 64; d <<= 1) {
                float ov = __shfl_xor(mv, d);
                int   oo = __shfl_xor(mo, d);
                if (ov > mv || (ov == mv && oo < mo)) { mv = ov; mo = oo; }
            }

            // gumbel-softmax denominator; y_soft at argmax = 1/se
            float se = 0.0f;
            #pragma unroll
            for (int j = j0; j < j0 + 5; ++j) se += expf(z[j] - mv);
            #pragma unroll
            for (int d = 1; d < 64; d <<= 1) se += __shfl_xor(se, d);
            float y = 1.0f / se;
            float q = (1.0f - y) + y;       // straight-through value

            // plain softmax for usage stats
            float m2 = acc[r][j0];
            #pragma unroll
            for (int j = j0 + 1; j < j0 + 5; ++j) m2 = fmaxf(m2, acc[r][j]);
            #pragma unroll
            for (int d = 1; d < 64; d <<= 1) m2 = fmaxf(m2, __shfl_xor(m2, d));
            float pe[5];
            float s2 = 0.0f;
            #pragma unroll
            for (int jj = 0; jj < 5; ++jj) {
                pe[jj] = expf(acc[r][j0 + jj] - m2);
                s2 += pe[jj];
            }
            #pragma unroll
            for (int d = 1; d < 64; d <<= 1) s2 += __shfl_xor(s2, d);
            if (valid) {
                #pragma unroll
                for (int jj = 0; jj < 5; ++jj)
                    atomicAdd(&uacc[lane + 64 * (j0 + jj)], pe[jj] / s2);
            }

            // quantized output: q * codebook[g, idx, :]
            const int c = mo - g * NC;
            const float2 cv = ((const float2*)(CB + ((size_t)g * NC + c) * DG))[lane];
            float2 ov2;
            ov2.x = q * cv.x;
            ov2.y = q * cv.y;
            ((float2*)(out + (size_t)row * (NG * DG) + g * DG))[lane] = ov2;
        }
    }

    __syncthreads();
    for (int i = t; i < GC; i += 256) atomicAdd(&gacc[i], uacc[i]);
}

__global__ void finalize_usage(const float* __restrict__ gacc,
                               const int* __restrict__ vlen,
                               float* __restrict__ usage_out)
{
    int total = 0;
    #pragma unroll
    for (int b = 0; b < NB; ++b) total += vlen[b];
    int o = threadIdx.x;
    if (o < GC) usage_out[o] = gacc[o] / (float)total;
}

extern "C" void kernel_launch(void* const* d_in, const int* in_sizes, int n_in,
                              void* d_out, int out_size, void* d_ws, size_t ws_size,
                              hipStream_t stream)
{
    const float* X    = (const float*)d_in[0];
    const int*   vlen = (const int*)d_in[1];
    const float* U    = (const float*)d_in[2];
    const float* W    = (const float*)d_in[3];
    const float* bias = (const float*)d_in[4];
    const float* CB   = (const float*)d_in[5];
    const float* T    = (const float*)d_in[6];
    float* out = (float*)d_out;

    float* Wt   = (float*)d_ws;                    // 512*640 floats
    float* gacc = (float*)d_ws + (size_t)DIN * GC; // 640 floats

    hipMemsetAsync(gacc, 0, GC * sizeof(float), stream);
    transpose_w<<<(GC * DIN + 255) / 256, 256, 0, stream>>>(W, Wt);
    fused_main<<<NROW / RT, 256, 0, stream>>>(X, vlen, U, Wt, bias, CB, T, out, gacc);
    finalize_usage<<<1, GC, 0, stream>>>(gacc, vlen, out + (size_t)NROW * (NG * DG));
}

// Round 5
// 481.196 us; speedup vs baseline: 20.2265x; 1.9283x over previous
//
#include <hip/hip_runtime.h>
#include <math.h>

#define NB 16
#define NS 4096
#define DIN 512
#define NG 2
#define NC 320
#define GC 640          // NG*NC
#define DG 128          // D_out / G
#define NROW (NB*NS)    // 65536
#define EPSV 1e-10f

typedef __attribute__((ext_vector_type(4))) float f32x4;
typedef __attribute__((ext_vector_type(8))) _Float16 f16x8;
typedef __attribute__((ext_vector_type(4))) _Float16 f16x4v;

// async global->LDS, 16B per lane; lds dest is wave-uniform base (+ lane*16 by HW)
__device__ __forceinline__ void gload_lds16(const void* g, void* l) {
    __builtin_amdgcn_global_load_lds(
        (const __attribute__((address_space(1))) void*)g,
        (__attribute__((address_space(3))) void*)l,
        16, 0, 0);
}

// ---------- split f32 -> (f16 hi, f16 lo*2048) ----------
__global__ __launch_bounds__(256) void cvt_split(
    const float* __restrict__ src, _Float16* __restrict__ h,
    _Float16* __restrict__ l, int n4)
{
    int i = blockIdx.x * 256 + threadIdx.x;
    if (i >= n4) return;
    float4 v = ((const float4*)src)[i];
    f16x4v vh, vl;
    float xs[4] = {v.x, v.y, v.z, v.w};
    #pragma unroll
    for (int j = 0; j < 4; ++j) {
        _Float16 hh = (_Float16)xs[j];
        vh[j] = hh;
        vl[j] = (_Float16)((xs[j] - (float)hh) * 2048.0f);
    }
    ((f16x4v*)h)[i] = vh;
    ((f16x4v*)l)[i] = vl;
}

// ---------- MFMA GEMM: logits[65536][640] = X[65536][512]*W^T + b ----------
// split-2 f16: logits = Ah*Bh + 2^-11*(Ah*Bl + Al*Bh)
__global__ __launch_bounds__(256, 2) void mfma_logits(
    const _Float16* __restrict__ Xh, const _Float16* __restrict__ Xl,
    const _Float16* __restrict__ Wh, const _Float16* __restrict__ Wl,
    const float* __restrict__ bias, float* __restrict__ logits)
{
    __shared__ _Float16 sA[2][2][128 * 32];   // [buf][h/l][row*32+k], 32 KB
    __shared__ _Float16 sB[2][2][128 * 32];   // 32 KB

    const int t = threadIdx.x;
    const int lane = t & 63;
    const int w = t >> 6;
    const int wm = w >> 1, wn = w & 1;

    // grid remap: 5 N-blocks of one M-panel land on the same XCD
    const int p = blockIdx.x;
    const int o = (p & 7) * 320 + (p >> 3);
    const int mb = o / 5, nb = o - mb * 5;
    const int row0 = mb * 128, n0 = nb * 128;

    // staging lane geometry: instr i covers rows 16i..16i+15, 4x16B slots/row
    const int rl = lane >> 2;                       // row within 16-row chunk
    const int sl = (lane & 3) ^ ((lane >> 3) & 3);  // pre-swizzled source slot

    auto stage = [&](int b, int k0) {
        #pragma unroll
        for (int j = 0; j < 2; ++j) {
            int i = 2 * w + j;                      // 0..7
            int ro = 16 * i + rl;
            size_t ga = (size_t)(row0 + ro) * DIN + k0 + 8 * sl;
            size_t gb = (size_t)(n0 + ro) * DIN + k0 + 8 * sl;
            gload_lds16(Xh + ga, &sA[b][0][i * 512]);
            gload_lds16(Xl + ga, &sA[b][1][i * 512]);
            gload_lds16(Wh + gb, &sB[b][0][i * 512]);
            gload_lds16(Wl + gb, &sB[b][1][i * 512]);
        }
    };

    f32x4 accA[4][4], accB[4][4];
    const f32x4 zz = {0.f, 0.f, 0.f, 0.f};
    #pragma unroll
    for (int mt = 0; mt < 4; ++mt)
        #pragma unroll
        for (int nt = 0; nt < 4; ++nt) { accA[mt][nt] = zz; accB[mt][nt] = zz; }

    stage(0, 0);
    __syncthreads();

    for (int ks = 0; ks < 16; ++ks) {
        const int cur = ks & 1;
        if (ks < 15) stage(cur ^ 1, (ks + 1) * 32);

        f16x8 ah[4], al[4], bh[4], bl[4];
        #pragma unroll
        for (int mt = 0; mt < 4; ++mt) {
            int r = wm * 64 + mt * 16 + (lane & 15);
            int idx = r * 32 + 8 * ((lane >> 4) ^ ((r >> 1) & 3));  // XOR de-conflict
            ah[mt] = *(const f16x8*)&sA[cur][0][idx];
            al[mt] = *(const f16x8*)&sA[cur][1][idx];
        }
        #pragma unroll
        for (int nt = 0; nt < 4; ++nt) {
            int r = wn * 64 + nt * 16 + (lane & 15);
            int idx = r * 32 + 8 * ((lane >> 4) ^ ((r >> 1) & 3));
            bh[nt] = *(const f16x8*)&sB[cur][0][idx];
            bl[nt] = *(const f16x8*)&sB[cur][1][idx];
        }
        #pragma unroll
        for (int mt = 0; mt < 4; ++mt)
            #pragma unroll
            for (int nt = 0; nt < 4; ++nt) {
                accA[mt][nt] = __builtin_amdgcn_mfma_f32_16x16x32_f16(ah[mt], bh[nt], accA[mt][nt], 0, 0, 0);
                accB[mt][nt] = __builtin_amdgcn_mfma_f32_16x16x32_f16(ah[mt], bl[nt], accB[mt][nt], 0, 0, 0);
                accB[mt][nt] = __builtin_amdgcn_mfma_f32_16x16x32_f16(al[mt], bh[nt], accB[mt][nt], 0, 0, 0);
            }
        __syncthreads();
    }

    // combine chains + bias, store f32 logits
    #pragma unroll
    for (int nt = 0; nt < 4; ++nt) {
        int col = n0 + wn * 64 + nt * 16 + (lane & 15);
        float bv = bias[col];
        #pragma unroll
        for (int mt = 0; mt < 4; ++mt) {
            #pragma unroll
            for (int q = 0; q < 4; ++q) {
                int row = row0 + wm * 64 + mt * 16 + (lane >> 4) * 4 + q;
                logits[(size_t)row * GC + col] =
                    accA[mt][nt][q] + accB[mt][nt][q] * (1.0f / 2048.0f) + bv;
            }
        }
    }
}

// ---------- epilogue (proven in round 3) ----------
#define RTB 32
__global__ __launch_bounds__(256, 8) void epilogue(
    const float* __restrict__ logits, const int* __restrict__ vlen,
    const float* __restrict__ U, const float* __restrict__ CB,
    const float* __restrict__ tptr, float* __restrict__ out,
    float* __restrict__ gacc)
{
    __shared__ float uacc[GC];
    const int t = threadIdx.x;
    const int lane = t & 63;
    const int wid = t >> 6;
    const int row0 = blockIdx.x * RTB;

    for (int i = t; i < GC; i += 256) uacc[i] = 0.0f;
    __syncthreads();

    const float T = *tptr;
    const int vl = vlen[row0 >> 12];

    #pragma unroll
    for (int r = 0; r < 8; ++r) {
        const int row = row0 + wid * 8 + r;
        const int ss = row & (NS - 1);
        const bool valid = ss < vl;

        float lg[10], z[10];
        #pragma unroll
        for (int j = 0; j < 10; ++j)
            lg[j] = logits[(size_t)row * GC + lane + 64 * j];
        #pragma unroll
        for (int j = 0; j < 10; ++j) {
            float u = U[(size_t)row * GC + lane + 64 * j];
            float gn = -logf(-logf(u + EPSV) + EPSV);
            z[j] = (lg[j] + gn) / T;
        }

        #pragma unroll
        for (int g = 0; g < 2; ++g) {
            const int j0 = g * 5;

            float mv = z[j0];
            int mo = lane + 64 * j0;
            #pragma unroll
            for (int j = j0 + 1; j < j0 + 5; ++j) {
                if (z[j] > mv) { mv = z[j]; mo = lane + 64 * j; }
            }
            #pragma unroll
            for (int d = 1; d < 64; d <<= 1) {
                float ov = __shfl_xor(mv, d);
                int   oo = __shfl_xor(mo, d);
                if (ov > mv || (ov == mv && oo < mo)) { mv = ov; mo = oo; }
            }

            float se = 0.0f;
            #pragma unroll
            for (int j = j0; j < j0 + 5; ++j) se += expf(z[j] - mv);
            #pragma unroll
            for (int d = 1; d < 64; d <<= 1) se += __shfl_xor(se, d);
            float y = 1.0f / se;
            float q = (1.0f - y) + y;

            float m2 = lg[j0];
            #pragma unroll
            for (int j = j0 + 1; j < j0 + 5; ++j) m2 = fmaxf(m2, lg[j]);
            #pragma unroll
            for (int d = 1; d < 64; d <<= 1) m2 = fmaxf(m2, __shfl_xor(m2, d));
            float pe[5];
            float s2 = 0.0f;
            #pragma unroll
            for (int jj = 0; jj < 5; ++jj) {
                pe[jj] = expf(lg[j0 + jj] - m2);
                s2 += pe[jj];
            }
            #pragma unroll
            for (int d = 1; d < 64; d <<= 1) s2 += __shfl_xor(s2, d);
            if (valid) {
                #pragma unroll
                for (int jj = 0; jj < 5; ++jj)
                    atomicAdd(&uacc[lane + 64 * (j0 + jj)], pe[jj] / s2);
            }

            const int c = mo - g * NC;
            const float2 cv = ((const float2*)(CB + ((size_t)g * NC + c) * DG))[lane];
            float2 ov2;
            ov2.x = q * cv.x;
            ov2.y = q * cv.y;
            ((float2*)(out + (size_t)row * (NG * DG) + g * DG))[lane] = ov2;
        }
    }

    __syncthreads();
    for (int i = t; i < GC; i += 256) atomicAdd(&gacc[i], uacc[i]);
}

__global__ void finalize_usage(const float* __restrict__ gacc,
                               const int* __restrict__ vlen,
                               float* __restrict__ usage_out)
{
    int total = 0;
    #pragma unroll
    for (int b = 0; b < NB; ++b) total += vlen[b];
    int o = threadIdx.x;
    if (o < GC) usage_out[o] = gacc[o] / (float)total;
}

// ---------- fallback path (round-4, f32 VALU, proven 928 us) ----------
#define RT 32
#define KC 8
#define NIT (DIN/KC)

__global__ void transpose_w(const float* __restrict__ W, float* __restrict__ Wt) {
    int idx = blockIdx.x * 256 + threadIdx.x;
    if (idx >= GC * DIN) return;
    int k = idx / GC, o = idx - k * GC;
    Wt[idx] = W[(size_t)o * DIN + k];
}

__global__ __launch_bounds__(256, 2) void fused_main(
    const float* __restrict__ X, const int* __restrict__ vlen,
    const float* __restrict__ U, const float* __restrict__ Wt,
    const float* __restrict__ bias, const float* __restrict__ CB,
    const float* __restrict__ tptr, float* __restrict__ out,
    float* __restrict__ gacc)
{
    __shared__ __align__(16) float WtC[2][KC][GC];
    __shared__ __align__(16) float AC[2][RT][KC];
    __shared__ float uacc[GC];

    const int t = threadIdx.x;
    const int lane = t & 63;
    const int wid = t >> 6;
    const int row0 = blockIdx.x * RT;

    for (int i = t; i < GC; i += 256) uacc[i] = 0.0f;

    float acc[8][10];
    #pragma unroll
    for (int r = 0; r < 8; ++r)
        #pragma unroll
        for (int j = 0; j < 10; ++j) acc[r][j] = 0.0f;

    auto stage = [&](int b, int k0) {
        const float* gw = Wt + (size_t)k0 * GC;
        #pragma unroll
        for (int i = 0; i < 5; ++i) {
            int base = (wid * 5 + i) * 256;
            gload_lds16(gw + base + 4 * lane, &WtC[b][0][0] + base);
        }
        if (wid == 0) {
            const float* gx = X + (size_t)(row0 + (lane >> 1)) * DIN + k0 + 4 * (lane & 1);
            gload_lds16(gx, &AC[b][0][0]);
        }
    };

    stage(0, 0);
    __syncthreads();

    int cur = 0;
    for (int it = 0; it < NIT; ++it) {
        if (it + 1 < NIT) stage(cur ^ 1, (it + 1) * KC);
        #pragma unroll
        for (int kk = 0; kk < KC; ++kk) {
            float w[10];
            #pragma unroll
            for (int j = 0; j < 10; ++j) w[j] = WtC[cur][kk][lane + 64 * j];
            #pragma unroll
            for (int r = 0; r < 8; ++r) {
                float a = AC[cur][wid * 8 + r][kk];
                #pragma unroll
                for (int j = 0; j < 10; ++j) acc[r][j] = fmaf(a, w[j], acc[r][j]);
            }
        }
        __syncthreads();
        cur ^= 1;
    }

    float bv[10];
    #pragma unroll
    for (int j = 0; j < 10; ++j) bv[j] = bias[lane + 64 * j];
    #pragma unroll
    for (int r = 0; r < 8; ++r)
        #pragma unroll
        for (int j = 0; j < 10; ++j) acc[r][j] += bv[j];

    const float T = *tptr;
    const int vl = vlen[row0 >> 12];

    #pragma unroll
    for (int r = 0; r < 8; ++r) {
        const int row = row0 + wid * 8 + r;
        const int ss = row & (NS - 1);
        const bool valid = ss < vl;

        float z[10];
        #pragma unroll
        for (int j = 0; j < 10; ++j) {
            float u = U[(size_t)row * GC + lane + 64 * j];
            float gn = -logf(-logf(u + EPSV) + EPSV);
            z[j] = (acc[r][j] + gn) / T;
        }

        #pragma unroll
        for (int g = 0; g < 2; ++g) {
            const int j0 = g * 5;
            float mv = z[j0];
            int mo = lane + 64 * j0;
            #pragma unroll
            for (int j = j0 + 1; j < j0 + 5; ++j) {
                if (z[j] > mv) { mv = z[j]; mo = lane + 64 * j; }
            }
            #pragma unroll
            for (int d = 1; d < 64; d <<= 1) {
                float ov = __shfl_xor(mv, d);
                int   oo = __shfl_xor(mo, d);
                if (ov > mv || (ov == mv && oo < mo)) { mv = ov; mo = oo; }
            }
            float se = 0.0f;
            #pragma unroll
            for (int j = j0; j < j0 + 5; ++j) se += expf(z[j] - mv);
            #pragma unroll
            for (int d = 1; d < 64; d <<= 1) se += __shfl_xor(se, d);
            float y = 1.0f / se;
            float q = (1.0f - y) + y;

            float m2 = acc[r][j0];
            #pragma unroll
            for (int j = j0 + 1; j < j0 + 5; ++j) m2 = fmaxf(m2, acc[r][j]);
            #pragma unroll
            for (int d = 1; d < 64; d <<= 1) m2 = fmaxf(m2, __shfl_xor(m2, d));
            float pe[5];
            float s2 = 0.0f;
            #pragma unroll
            for (int jj = 0; jj < 5; ++jj) {
                pe[jj] = expf(acc[r][j0 + jj] - m2);
                s2 += pe[jj];
            }
            #pragma unroll
            for (int d = 1; d < 64; d <<= 1) s2 += __shfl_xor(s2, d);
            if (valid) {
                #pragma unroll
                for (int jj = 0; jj < 5; ++jj)
                    atomicAdd(&uacc[lane + 64 * (j0 + jj)], pe[jj] / s2);
            }

            const int c = mo - g * NC;
            const float2 cv = ((const float2*)(CB + ((size_t)g * NC + c) * DG))[lane];
            float2 ov2;
            ov2.x = q * cv.x;
            ov2.y = q * cv.y;
            ((float2*)(out + (size_t)row * (NG * DG) + g * DG))[lane] = ov2;
        }
    }

    __syncthreads();
    for (int i = t; i < GC; i += 256) atomicAdd(&gacc[i], uacc[i]);
}

extern "C" void kernel_launch(void* const* d_in, const int* in_sizes, int n_in,
                              void* d_out, int out_size, void* d_ws, size_t ws_size,
                              hipStream_t stream)
{
    const float* X    = (const float*)d_in[0];
    const int*   vlen = (const int*)d_in[1];
    const float* U    = (const float*)d_in[2];
    const float* W    = (const float*)d_in[3];
    const float* bias = (const float*)d_in[4];
    const float* CB   = (const float*)d_in[5];
    const float* T    = (const float*)d_in[6];
    float* out = (float*)d_out;

    char* ws = (char*)d_ws;
    // layout (bytes)
    float*     Wt   = (float*)ws;                               // 1,310,720
    float*     gacc = (float*)(ws + 1310720);                   // 2,560
    _Float16*  Whh  = (_Float16*)(ws + 1313792);                // 655,360
    _Float16*  Wll  = (_Float16*)(ws + 1969152);                // 655,360
    _Float16*  Xhh  = (_Float16*)(ws + 2624512);                // 67,108,864
    _Float16*  Xll  = (_Float16*)(ws + 69733376);               // 67,108,864
    float*     lgts = (float*)(ws + 136842240);                 // 167,772,160
    const size_t need = 136842240ull + 167772160ull;            // ~290.6 MB

    hipMemsetAsync(gacc, 0, GC * sizeof(float), stream);

    if (ws_size >= need) {
        const int nx4 = NROW * DIN / 4;   // 8,388,608
        const int nw4 = GC * DIN / 4;     // 81,920
        cvt_split<<<(nx4 + 255) / 256, 256, 0, stream>>>(X, Xhh, Xll, nx4);
        cvt_split<<<(nw4 + 255) / 256, 256, 0, stream>>>(W, Whh, Wll, nw4);
        mfma_logits<<<(NROW / 128) * 5, 256, 0, stream>>>(Xhh, Xll, Whh, Wll, bias, lgts);
        epilogue<<<NROW / RTB, 256, 0, stream>>>(lgts, vlen, U, CB, T, out, gacc);
    } else {
        transpose_w<<<(GC * DIN + 255) / 256, 256, 0, stream>>>(W, Wt);
        fused_main<<<NROW / RT, 256, 0, stream>>>(X, vlen, U, Wt, bias, CB, T, out, gacc);
    }
    finalize_usage<<<1, GC, 0, stream>>>(gacc, vlen, out + (size_t)NROW * (NG * DG));
}

// Round 6
// 362.684 us; speedup vs baseline: 26.8357x; 1.3268x over previous
//
#include <hip/hip_runtime.h>
#include <math.h>

#define NB 16
#define NS 4096
#define DIN 512
#define NG 2
#define NC 320
#define GC 640          // NG*NC
#define DG 128          // D_out / G
#define NROW (NB*NS)    // 65536
#define EPSV 1e-10f

typedef __attribute__((ext_vector_type(4))) float f32x4;
typedef __attribute__((ext_vector_type(8))) _Float16 f16x8;
typedef __attribute__((ext_vector_type(4))) _Float16 f16x4v;

// async global->LDS, 16B per lane; lds dest is wave-uniform base (+ lane*16 by HW)
__device__ __forceinline__ void gload_lds16(const void* g, void* l) {
    __builtin_amdgcn_global_load_lds(
        (const __attribute__((address_space(1))) void*)g,
        (__attribute__((address_space(3))) void*)l,
        16, 0, 0);
}

// ---------- split f32 -> (f16 hi, f16 lo*2048) ----------
__global__ __launch_bounds__(256) void cvt_split(
    const float* __restrict__ src, _Float16* __restrict__ h,
    _Float16* __restrict__ l, int n4)
{
    int i = blockIdx.x * 256 + threadIdx.x;
    if (i >= n4) return;
    float4 v = ((const float4*)src)[i];
    f16x4v vh, vl;
    float xs[4] = {v.x, v.y, v.z, v.w};
    #pragma unroll
    for (int j = 0; j < 4; ++j) {
        _Float16 hh = (_Float16)xs[j];
        vh[j] = hh;
        vl[j] = (_Float16)((xs[j] - (float)hh) * 2048.0f);
    }
    ((f16x4v*)h)[i] = vh;
    ((f16x4v*)l)[i] = vl;
}

// ---------- MFMA GEMM: logits[65536][640] = X[65536][512]*W^T + b ----------
// split-2 f16: logits = Ah*Bh + 2^-11*(Ah*Bl + Al*Bh)
__global__ __launch_bounds__(256, 2) void mfma_logits(
    const _Float16* __restrict__ Xh, const _Float16* __restrict__ Xl,
    const _Float16* __restrict__ Wh, const _Float16* __restrict__ Wl,
    const float* __restrict__ bias, float* __restrict__ logits)
{
    __shared__ _Float16 sA[2][2][128 * 32];   // [buf][h/l][row*32+k], 32 KB
    __shared__ _Float16 sB[2][2][128 * 32];   // 32 KB

    const int t = threadIdx.x;
    const int lane = t & 63;
    const int w = t >> 6;
    const int wm = w >> 1, wn = w & 1;

    // grid remap: 5 N-blocks of one M-panel land on the same XCD
    const int p = blockIdx.x;
    const int o = (p & 7) * 320 + (p >> 3);
    const int mb = o / 5, nb = o - mb * 5;
    const int row0 = mb * 128, n0 = nb * 128;

    // staging lane geometry: instr i covers rows 16i..16i+15, 4x16B slots/row
    const int rl = lane >> 2;                       // row within 16-row chunk
    const int sl = (lane & 3) ^ ((lane >> 3) & 3);  // pre-swizzled source slot

    auto stage = [&](int b, int k0) {
        #pragma unroll
        for (int j = 0; j < 2; ++j) {
            int i = 2 * w + j;                      // 0..7
            int ro = 16 * i + rl;
            size_t ga = (size_t)(row0 + ro) * DIN + k0 + 8 * sl;
            size_t gb = (size_t)(n0 + ro) * DIN + k0 + 8 * sl;
            gload_lds16(Xh + ga, &sA[b][0][i * 512]);
            gload_lds16(Xl + ga, &sA[b][1][i * 512]);
            gload_lds16(Wh + gb, &sB[b][0][i * 512]);
            gload_lds16(Wl + gb, &sB[b][1][i * 512]);
        }
    };

    f32x4 accA[4][4], accB[4][4];
    const f32x4 zz = {0.f, 0.f, 0.f, 0.f};
    #pragma unroll
    for (int mt = 0; mt < 4; ++mt)
        #pragma unroll
        for (int nt = 0; nt < 4; ++nt) { accA[mt][nt] = zz; accB[mt][nt] = zz; }

    stage(0, 0);
    __syncthreads();

    for (int ks = 0; ks < 16; ++ks) {
        const int cur = ks & 1;
        if (ks < 15) stage(cur ^ 1, (ks + 1) * 32);

        f16x8 ah[4], al[4], bh[4], bl[4];
        #pragma unroll
        for (int mt = 0; mt < 4; ++mt) {
            int r = wm * 64 + mt * 16 + (lane & 15);
            int idx = r * 32 + 8 * ((lane >> 4) ^ ((r >> 1) & 3));  // XOR de-conflict
            ah[mt] = *(const f16x8*)&sA[cur][0][idx];
            al[mt] = *(const f16x8*)&sA[cur][1][idx];
        }
        #pragma unroll
        for (int nt = 0; nt < 4; ++nt) {
            int r = wn * 64 + nt * 16 + (lane & 15);
            int idx = r * 32 + 8 * ((lane >> 4) ^ ((r >> 1) & 3));
            bh[nt] = *(const f16x8*)&sB[cur][0][idx];
            bl[nt] = *(const f16x8*)&sB[cur][1][idx];
        }
        #pragma unroll
        for (int mt = 0; mt < 4; ++mt)
            #pragma unroll
            for (int nt = 0; nt < 4; ++nt) {
                accA[mt][nt] = __builtin_amdgcn_mfma_f32_16x16x32_f16(ah[mt], bh[nt], accA[mt][nt], 0, 0, 0);
                accB[mt][nt] = __builtin_amdgcn_mfma_f32_16x16x32_f16(ah[mt], bl[nt], accB[mt][nt], 0, 0, 0);
                accB[mt][nt] = __builtin_amdgcn_mfma_f32_16x16x32_f16(al[mt], bh[nt], accB[mt][nt], 0, 0, 0);
            }
        __syncthreads();
    }

    // combine chains + bias, store f32 logits
    #pragma unroll
    for (int nt = 0; nt < 4; ++nt) {
        int col = n0 + wn * 64 + nt * 16 + (lane & 15);
        float bv = bias[col];
        #pragma unroll
        for (int mt = 0; mt < 4; ++mt) {
            #pragma unroll
            for (int q = 0; q < 4; ++q) {
                int row = row0 + wm * 64 + mt * 16 + (lane >> 4) * 4 + q;
                logits[(size_t)row * GC + col] =
                    accA[mt][nt][q] + accB[mt][nt][q] * (1.0f / 2048.0f) + bv;
            }
        }
    }
}

// ---------- epilogue (q==1.0 exactly -> no gumbel-softmax denom needed) ----------
#define RTB 32
__global__ __launch_bounds__(256, 8) void epilogue(
    const float* __restrict__ logits, const int* __restrict__ vlen,
    const float* __restrict__ U, const float* __restrict__ CB,
    float* __restrict__ out, float* __restrict__ gacc)
{
    __shared__ float uacc[GC];
    const int t = threadIdx.x;
    const int lane = t & 63;
    const int wid = t >> 6;
    const int row0 = blockIdx.x * RTB;

    for (int i = t; i < GC; i += 256) uacc[i] = 0.0f;
    __syncthreads();

    const int vl = vlen[row0 >> 12];

    float ureg[10];
    #pragma unroll
    for (int j = 0; j < 10; ++j) ureg[j] = 0.0f;

    #pragma unroll
    for (int r = 0; r < 8; ++r) {
        const int row = row0 + wid * 8 + r;
        const int ss = row & (NS - 1);
        const bool valid = ss < vl;

        float lg[10], zz[10];
        #pragma unroll
        for (int j = 0; j < 10; ++j)
            lg[j] = logits[(size_t)row * GC + lane + 64 * j];
        // argmax((lg+gn)/T) == argmax(lg+gn)  (T=2 exact power-of-two scaling)
        #pragma unroll
        for (int j = 0; j < 10; ++j) {
            float u = U[(size_t)row * GC + lane + 64 * j];
            float gn = -logf(-logf(u + EPSV) + EPSV);   // precise: argmax-critical
            zz[j] = lg[j] + gn;
        }

        #pragma unroll
        for (int g = 0; g < 2; ++g) {
            const int j0 = g * 5;

            // max+argmax (first-occurrence tie-break) over 320 cols
            float mv = zz[j0];
            int mo = lane + 64 * j0;
            #pragma unroll
            for (int j = j0 + 1; j < j0 + 5; ++j) {
                if (zz[j] > mv) { mv = zz[j]; mo = lane + 64 * j; }
            }
            #pragma unroll
            for (int d = 1; d < 64; d <<= 1) {
                float ov = __shfl_xor(mv, d);
                int   oo = __shfl_xor(mo, d);
                if (ov > mv || (ov == mv && oo < mo)) { mv = ov; mo = oo; }
            }

            // plain softmax for usage stats (__expf: tolerance 7e-5 abs, safe)
            float m2 = lg[j0];
            #pragma unroll
            for (int j = j0 + 1; j < j0 + 5; ++j) m2 = fmaxf(m2, lg[j]);
            #pragma unroll
            for (int d = 1; d < 64; d <<= 1) m2 = fmaxf(m2, __shfl_xor(m2, d));
            float pe[5];
            float s2 = 0.0f;
            #pragma unroll
            for (int jj = 0; jj < 5; ++jj) {
                pe[jj] = __expf(lg[j0 + jj] - m2);
                s2 += pe[jj];
            }
            #pragma unroll
            for (int d = 1; d < 64; d <<= 1) s2 += __shfl_xor(s2, d);
            if (valid) {
                const float inv = 1.0f / s2;
                #pragma unroll
                for (int jj = 0; jj < 5; ++jj) ureg[j0 + jj] += pe[jj] * inv;
            }

            // straight-through output == codebook row exactly (q == 1.0f proven)
            const int c = mo - g * NC;
            const float2 cv = ((const float2*)(CB + ((size_t)g * NC + c) * DG))[lane];
            ((float2*)(out + (size_t)row * (NG * DG) + g * DG))[lane] = cv;
        }
    }

    #pragma unroll
    for (int j = 0; j < 10; ++j)
        atomicAdd(&uacc[lane + 64 * j], ureg[j]);

    __syncthreads();
    for (int i = t; i < GC; i += 256) atomicAdd(&gacc[i], uacc[i]);
}

__global__ void finalize_usage(const float* __restrict__ gacc,
                               const int* __restrict__ vlen,
                               float* __restrict__ usage_out)
{
    int total = 0;
    #pragma unroll
    for (int b = 0; b < NB; ++b) total += vlen[b];
    int o = threadIdx.x;
    if (o < GC) usage_out[o] = gacc[o] / (float)total;
}

// ---------- fallback path (round-4, f32 VALU, proven 928 us) ----------
#define RT 32
#define KC 8
#define NIT (DIN/KC)

__global__ void transpose_w(const float* __restrict__ W, float* __restrict__ Wt) {
    int idx = blockIdx.x * 256 + threadIdx.x;
    if (idx >= GC * DIN) return;
    int k = idx / GC, o = idx - k * GC;
    Wt[idx] = W[(size_t)o * DIN + k];
}

__global__ __launch_bounds__(256, 2) void fused_main(
    const float* __restrict__ X, const int* __restrict__ vlen,
    const float* __restrict__ U, const float* __restrict__ Wt,
    const float* __restrict__ bias, const float* __restrict__ CB,
    const float* __restrict__ tptr, float* __restrict__ out,
    float* __restrict__ gacc)
{
    __shared__ __align__(16) float WtC[2][KC][GC];
    __shared__ __align__(16) float AC[2][RT][KC];
    __shared__ float uacc[GC];

    const int t = threadIdx.x;
    const int lane = t & 63;
    const int wid = t >> 6;
    const int row0 = blockIdx.x * RT;

    for (int i = t; i < GC; i += 256) uacc[i] = 0.0f;

    float acc[8][10];
    #pragma unroll
    for (int r = 0; r < 8; ++r)
        #pragma unroll
        for (int j = 0; j < 10; ++j) acc[r][j] = 0.0f;

    auto stage = [&](int b, int k0) {
        const float* gw = Wt + (size_t)k0 * GC;
        #pragma unroll
        for (int i = 0; i < 5; ++i) {
            int base = (wid * 5 + i) * 256;
            gload_lds16(gw + base + 4 * lane, &WtC[b][0][0] + base);
        }
        if (wid == 0) {
            const float* gx = X + (size_t)(row0 + (lane >> 1)) * DIN + k0 + 4 * (lane & 1);
            gload_lds16(gx, &AC[b][0][0]);
        }
    };

    stage(0, 0);
    __syncthreads();

    int cur = 0;
    for (int it = 0; it < NIT; ++it) {
        if (it + 1 < NIT) stage(cur ^ 1, (it + 1) * KC);
        #pragma unroll
        for (int kk = 0; kk < KC; ++kk) {
            float w[10];
            #pragma unroll
            for (int j = 0; j < 10; ++j) w[j] = WtC[cur][kk][lane + 64 * j];
            #pragma unroll
            for (int r = 0; r < 8; ++r) {
                float a = AC[cur][wid * 8 + r][kk];
                #pragma unroll
                for (int j = 0; j < 10; ++j) acc[r][j] = fmaf(a, w[j], acc[r][j]);
            }
        }
        __syncthreads();
        cur ^= 1;
    }

    float bv[10];
    #pragma unroll
    for (int j = 0; j < 10; ++j) bv[j] = bias[lane + 64 * j];
    #pragma unroll
    for (int r = 0; r < 8; ++r)
        #pragma unroll
        for (int j = 0; j < 10; ++j) acc[r][j] += bv[j];

    const float T = *tptr;
    const int vl = vlen[row0 >> 12];

    #pragma unroll
    for (int r = 0; r < 8; ++r) {
        const int row = row0 + wid * 8 + r;
        const int ss = row & (NS - 1);
        const bool valid = ss < vl;

        float z[10];
        #pragma unroll
        for (int j = 0; j < 10; ++j) {
            float u = U[(size_t)row * GC + lane + 64 * j];
            float gn = -logf(-logf(u + EPSV) + EPSV);
            z[j] = (acc[r][j] + gn) / T;
        }

        #pragma unroll
        for (int g = 0; g < 2; ++g) {
            const int j0 = g * 5;
            float mv = z[j0];
            int mo = lane + 64 * j0;
            #pragma unroll
            for (int j = j0 + 1; j < j0 + 5; ++j) {
                if (z[j] > mv) { mv = z[j]; mo = lane + 64 * j; }
            }
            #pragma unroll
            for (int d = 1; d < 64; d <<= 1) {
                float ov = __shfl_xor(mv, d);
                int   oo = __shfl_xor(mo, d);
                if (ov > mv || (ov == mv && oo < mo)) { mv = ov; mo = oo; }
            }
            float se = 0.0f;
            #pragma unroll
            for (int j = j0; j < j0 + 5; ++j) se += expf(z[j] - mv);
            #pragma unroll
            for (int d = 1; d < 64; d <<= 1) se += __shfl_xor(se, d);
            float y = 1.0f / se;
            float q = (1.0f - y) + y;

            float m2 = acc[r][j0];
            #pragma unroll
            for (int j = j0 + 1; j < j0 + 5; ++j) m2 = fmaxf(m2, acc[r][j]);
            #pragma unroll
            for (int d = 1; d < 64; d <<= 1) m2 = fmaxf(m2, __shfl_xor(m2, d));
            float pe[5];
            float s2 = 0.0f;
            #pragma unroll
            for (int jj = 0; jj < 5; ++jj) {
                pe[jj] = expf(acc[r][j0 + jj] - m2);
                s2 += pe[jj];
            }
            #pragma unroll
            for (int d = 1; d < 64; d <<= 1) s2 += __shfl_xor(s2, d);
            if (valid) {
                #pragma unroll
                for (int jj = 0; jj < 5; ++jj)
                    atomicAdd(&uacc[lane + 64 * (j0 + jj)], pe[jj] / s2);
            }

            const int c = mo - g * NC;
            const float2 cv = ((const float2*)(CB + ((size_t)g * NC + c) * DG))[lane];
            float2 ov2;
            ov2.x = q * cv.x;
            ov2.y = q * cv.y;
            ((float2*)(out + (size_t)row * (NG * DG) + g * DG))[lane] = ov2;
        }
    }

    __syncthreads();
    for (int i = t; i < GC; i += 256) atomicAdd(&gacc[i], uacc[i]);
}

extern "C" void kernel_launch(void* const* d_in, const int* in_sizes, int n_in,
                              void* d_out, int out_size, void* d_ws, size_t ws_size,
                              hipStream_t stream)
{
    const float* X    = (const float*)d_in[0];
    const int*   vlen = (const int*)d_in[1];
    const float* U    = (const float*)d_in[2];
    const float* W    = (const float*)d_in[3];
    const float* bias = (const float*)d_in[4];
    const float* CB   = (const float*)d_in[5];
    const float* T    = (const float*)d_in[6];
    float* out = (float*)d_out;

    char* ws = (char*)d_ws;
    // layout (bytes)
    float*     Wt   = (float*)ws;                               // 1,310,720
    float*     gacc = (float*)(ws + 1310720);                   // 2,560
    _Float16*  Whh  = (_Float16*)(ws + 1313792);                // 655,360
    _Float16*  Wll  = (_Float16*)(ws + 1969152);                // 655,360
    _Float16*  Xhh  = (_Float16*)(ws + 2624512);                // 67,108,864
    _Float16*  Xll  = (_Float16*)(ws + 69733376);               // 67,108,864
    float*     lgts = (float*)(ws + 136842240);                 // 167,772,160
    const size_t need = 136842240ull + 167772160ull;            // ~290.6 MB

    hipMemsetAsync(gacc, 0, GC * sizeof(float), stream);

    if (ws_size >= need) {
        const int nx4 = NROW * DIN / 4;   // 8,388,608
        const int nw4 = GC * DIN / 4;     // 81,920
        cvt_split<<<(nx4 + 255) / 256, 256, 0, stream>>>(X, Xhh, Xll, nx4);
        cvt_split<<<(nw4 + 255) / 256, 256, 0, stream>>>(W, Whh, Wll, nw4);
        mfma_logits<<<(NROW / 128) * 5, 256, 0, stream>>>(Xhh, Xll, Whh, Wll, bias, lgts);
        epilogue<<<NROW / RTB, 256, 0, stream>>>(lgts, vlen, U, CB, out, gacc);
    } else {
        transpose_w<<<(GC * DIN + 255) / 256, 256, 0, stream>>>(W, Wt);
        fused_main<<<NROW / RT, 256, 0, stream>>>(X, vlen, U, Wt, bias, CB, T, out, gacc);
    }
    finalize_usage<<<1, GC, 0, stream>>>(gacc, vlen, out + (size_t)NROW * (NG * DG));
}

// Round 7
// 332.954 us; speedup vs baseline: 29.2320x; 1.0893x over previous
//
#include <hip/hip_runtime.h>
#include <math.h>

#define NB 16
#define NS 4096
#define DIN 512
#define NG 2
#define NC 320
#define GC 640          // NG*NC
#define DG 128          // D_out / G
#define NROW (NB*NS)    // 65536
#define EPSV 1e-10f

typedef __attribute__((ext_vector_type(4))) float f32x4;
typedef __attribute__((ext_vector_type(8))) _Float16 f16x8;
typedef __attribute__((ext_vector_type(4))) _Float16 f16x4v;

// async global->LDS, 16B per lane; lds dest is wave-uniform base (+ lane*16 by HW)
__device__ __forceinline__ void gload_lds16(const void* g, void* l) {
    __builtin_amdgcn_global_load_lds(
        (const __attribute__((address_space(1))) void*)g,
        (__attribute__((address_space(3))) void*)l,
        16, 0, 0);
}

// ---------- split f32 -> (f16 hi, f16 lo*2048) ----------
__global__ __launch_bounds__(256) void cvt_split(
    const float* __restrict__ src, _Float16* __restrict__ h,
    _Float16* __restrict__ l, int n4)
{
    int i = blockIdx.x * 256 + threadIdx.x;
    if (i >= n4) return;
    float4 v = ((const float4*)src)[i];
    f16x4v vh, vl;
    float xs[4] = {v.x, v.y, v.z, v.w};
    #pragma unroll
    for (int j = 0; j < 4; ++j) {
        _Float16 hh = (_Float16)xs[j];
        vh[j] = hh;
        vl[j] = (_Float16)((xs[j] - (float)hh) * 2048.0f);
    }
    ((f16x4v*)h)[i] = vh;
    ((f16x4v*)l)[i] = vl;
}

// ---------- MFMA GEMM: logits[65536][640] = X[65536][512]*W^T + b ----------
// split-2 f16: logits = Ah*Bh + 2^-11*(Ah*Bl + Al*Bh)
__global__ __launch_bounds__(256, 2) void mfma_logits(
    const _Float16* __restrict__ Xh, const _Float16* __restrict__ Xl,
    const _Float16* __restrict__ Wh, const _Float16* __restrict__ Wl,
    const float* __restrict__ bias, float* __restrict__ logits)
{
    __shared__ _Float16 sA[2][2][128 * 32];   // [buf][h/l][row*32+k], 32 KB
    __shared__ _Float16 sB[2][2][128 * 32];   // 32 KB

    const int t = threadIdx.x;
    const int lane = t & 63;
    const int w = t >> 6;
    const int wm = w >> 1, wn = w & 1;

    // grid remap: 5 N-blocks of one M-panel land on the same XCD
    const int p = blockIdx.x;
    const int o = (p & 7) * 320 + (p >> 3);
    const int mb = o / 5, nb = o - mb * 5;
    const int row0 = mb * 128, n0 = nb * 128;

    // staging lane geometry: instr i covers rows 16i..16i+15, 4x16B slots/row
    const int rl = lane >> 2;                       // row within 16-row chunk
    const int sl = (lane & 3) ^ ((lane >> 3) & 3);  // pre-swizzled source slot

    auto stage = [&](int b, int k0) {
        #pragma unroll
        for (int j = 0; j < 2; ++j) {
            int i = 2 * w + j;                      // 0..7
            int ro = 16 * i + rl;
            size_t ga = (size_t)(row0 + ro) * DIN + k0 + 8 * sl;
            size_t gb = (size_t)(n0 + ro) * DIN + k0 + 8 * sl;
            gload_lds16(Xh + ga, &sA[b][0][i * 512]);
            gload_lds16(Xl + ga, &sA[b][1][i * 512]);
            gload_lds16(Wh + gb, &sB[b][0][i * 512]);
            gload_lds16(Wl + gb, &sB[b][1][i * 512]);
        }
    };

    f32x4 accA[4][4], accB[4][4];
    const f32x4 zz = {0.f, 0.f, 0.f, 0.f};
    #pragma unroll
    for (int mt = 0; mt < 4; ++mt)
        #pragma unroll
        for (int nt = 0; nt < 4; ++nt) { accA[mt][nt] = zz; accB[mt][nt] = zz; }

    stage(0, 0);
    __syncthreads();

    for (int ks = 0; ks < 16; ++ks) {
        const int cur = ks & 1;
        if (ks < 15) stage(cur ^ 1, (ks + 1) * 32);

        f16x8 ah[4], al[4], bh[4], bl[4];
        #pragma unroll
        for (int mt = 0; mt < 4; ++mt) {
            int r = wm * 64 + mt * 16 + (lane & 15);
            int idx = r * 32 + 8 * ((lane >> 4) ^ ((r >> 1) & 3));  // XOR de-conflict
            ah[mt] = *(const f16x8*)&sA[cur][0][idx];
            al[mt] = *(const f16x8*)&sA[cur][1][idx];
        }
        #pragma unroll
        for (int nt = 0; nt < 4; ++nt) {
            int r = wn * 64 + nt * 16 + (lane & 15);
            int idx = r * 32 + 8 * ((lane >> 4) ^ ((r >> 1) & 3));
            bh[nt] = *(const f16x8*)&sB[cur][0][idx];
            bl[nt] = *(const f16x8*)&sB[cur][1][idx];
        }
        #pragma unroll
        for (int mt = 0; mt < 4; ++mt)
            #pragma unroll
            for (int nt = 0; nt < 4; ++nt) {
                accA[mt][nt] = __builtin_amdgcn_mfma_f32_16x16x32_f16(ah[mt], bh[nt], accA[mt][nt], 0, 0, 0);
                accB[mt][nt] = __builtin_amdgcn_mfma_f32_16x16x32_f16(ah[mt], bl[nt], accB[mt][nt], 0, 0, 0);
                accB[mt][nt] = __builtin_amdgcn_mfma_f32_16x16x32_f16(al[mt], bh[nt], accB[mt][nt], 0, 0, 0);
            }
        __syncthreads();
    }

    // combine chains + bias, store f32 logits
    #pragma unroll
    for (int nt = 0; nt < 4; ++nt) {
        int col = n0 + wn * 64 + nt * 16 + (lane & 15);
        float bv = bias[col];
        #pragma unroll
        for (int mt = 0; mt < 4; ++mt) {
            #pragma unroll
            for (int q = 0; q < 4; ++q) {
                int row = row0 + wm * 64 + mt * 16 + (lane >> 4) * 4 + q;
                logits[(size_t)row * GC + col] =
                    accA[mt][nt][q] + accB[mt][nt][q] * (1.0f / 2048.0f) + bv;
            }
        }
    }
}

// ---------- epilogue: ballot-argmax, unstabilized usage softmax ----------
#define RTB 32
__global__ __launch_bounds__(256, 8) void epilogue(
    const float* __restrict__ logits, const int* __restrict__ vlen,
    const float* __restrict__ U, const float* __restrict__ CB,
    float* __restrict__ out, float* __restrict__ gacc)
{
    __shared__ float uacc[GC];
    const int t = threadIdx.x;
    const int lane = t & 63;
    const int wid = t >> 6;
    const int row0 = blockIdx.x * RTB;

    for (int i = t; i < GC; i += 256) uacc[i] = 0.0f;
    __syncthreads();

    const int vl = vlen[row0 >> 12];

    float ureg[10];
    #pragma unroll
    for (int j = 0; j < 10; ++j) ureg[j] = 0.0f;

    #pragma unroll
    for (int r = 0; r < 8; ++r) {
        const int row = row0 + wid * 8 + r;
        const bool valid = (row & (NS - 1)) < vl;

        float lg[10], zz[10];
        #pragma unroll
        for (int j = 0; j < 10; ++j)
            lg[j] = logits[(size_t)row * GC + lane + 64 * j];
        // z = lg + gumbel; argmax((lg+gn)/T) == argmax(lg+gn), T=2 exact
        #pragma unroll
        for (int j = 0; j < 10; ++j) {
            float u = U[(size_t)row * GC + lane + 64 * j];
            zz[j] = lg[j] - logf(-logf(u + EPSV) + EPSV);   // precise: argmax-critical
        }

        #pragma unroll
        for (int g = 0; g < 2; ++g) {
            const int j0 = g * 5;

            // exact max over 320 (value-only butterfly: 6 DS ops)
            float mv = zz[j0];
            #pragma unroll
            for (int j = j0 + 1; j < j0 + 5; ++j) mv = fmaxf(mv, zz[j]);
            #pragma unroll
            for (int d = 1; d < 64; d <<= 1) mv = fmaxf(mv, __shfl_xor(mv, d));

            // first-occurrence argmax via ballots (no DS pipe, no serial chain).
            // global idx = lane + 64*j  ->  minimize j first, then lane.
            int c = 0;
            #pragma unroll
            for (int jj = 4; jj >= 0; --jj) {
                unsigned long long b = __ballot(zz[j0 + jj] == mv);
                if (b) c = (__ffsll(b) - 1) + 64 * jj;
            }

            // usage softmax, stabilizer-free (logits O(1); softmax shift-invariant)
            float pe[5], s2 = 0.0f;
            #pragma unroll
            for (int jj = 0; jj < 5; ++jj) {
                pe[jj] = __expf(lg[j0 + jj]);
                s2 += pe[jj];
            }
            #pragma unroll
            for (int d = 1; d < 64; d <<= 1) s2 += __shfl_xor(s2, d);
            if (valid) {
                const float inv = 1.0f / s2;
                #pragma unroll
                for (int jj = 0; jj < 5; ++jj) ureg[j0 + jj] += pe[jj] * inv;
            }

            // straight-through output == selected codebook row exactly (q == 1.0)
            const float2 cv = ((const float2*)(CB + ((size_t)g * NC + c) * DG))[lane];
            ((float2*)(out + (size_t)row * (NG * DG) + g * DG))[lane] = cv;
        }
    }

    #pragma unroll
    for (int j = 0; j < 10; ++j)
        atomicAdd(&uacc[lane + 64 * j], ureg[j]);

    __syncthreads();
    for (int i = t; i < GC; i += 256) atomicAdd(&gacc[i], uacc[i]);
}

__global__ void finalize_usage(const float* __restrict__ gacc,
                               const int* __restrict__ vlen,
                               float* __restrict__ usage_out)
{
    int total = 0;
    #pragma unroll
    for (int b = 0; b < NB; ++b) total += vlen[b];
    int o = threadIdx.x;
    if (o < GC) usage_out[o] = gacc[o] / (float)total;
}

// ---------- fallback path (round-4, f32 VALU, proven 928 us) ----------
#define RT 32
#define KC 8
#define NIT (DIN/KC)

__global__ void transpose_w(const float* __restrict__ W, float* __restrict__ Wt) {
    int idx = blockIdx.x * 256 + threadIdx.x;
    if (idx >= GC * DIN) return;
    int k = idx / GC, o = idx - k * GC;
    Wt[idx] = W[(size_t)o * DIN + k];
}

__global__ __launch_bounds__(256, 2) void fused_main(
    const float* __restrict__ X, const int* __restrict__ vlen,
    const float* __restrict__ U, const float* __restrict__ Wt,
    const float* __restrict__ bias, const float* __restrict__ CB,
    const float* __restrict__ tptr, float* __restrict__ out,
    float* __restrict__ gacc)
{
    __shared__ __align__(16) float WtC[2][KC][GC];
    __shared__ __align__(16) float AC[2][RT][KC];
    __shared__ float uacc[GC];

    const int t = threadIdx.x;
    const int lane = t & 63;
    const int wid = t >> 6;
    const int row0 = blockIdx.x * RT;

    for (int i = t; i < GC; i += 256) uacc[i] = 0.0f;

    float acc[8][10];
    #pragma unroll
    for (int r = 0; r < 8; ++r)
        #pragma unroll
        for (int j = 0; j < 10; ++j) acc[r][j] = 0.0f;

    auto stage = [&](int b, int k0) {
        const float* gw = Wt + (size_t)k0 * GC;
        #pragma unroll
        for (int i = 0; i < 5; ++i) {
            int base = (wid * 5 + i) * 256;
            gload_lds16(gw + base + 4 * lane, &WtC[b][0][0] + base);
        }
        if (wid == 0) {
            const float* gx = X + (size_t)(row0 + (lane >> 1)) * DIN + k0 + 4 * (lane & 1);
            gload_lds16(gx, &AC[b][0][0]);
        }
    };

    stage(0, 0);
    __syncthreads();

    int cur = 0;
    for (int it = 0; it < NIT; ++it) {
        if (it + 1 < NIT) stage(cur ^ 1, (it + 1) * KC);
        #pragma unroll
        for (int kk = 0; kk < KC; ++kk) {
            float w[10];
            #pragma unroll
            for (int j = 0; j < 10; ++j) w[j] = WtC[cur][kk][lane + 64 * j];
            #pragma unroll
            for (int r = 0; r < 8; ++r) {
                float a = AC[cur][wid * 8 + r][kk];
                #pragma unroll
                for (int j = 0; j < 10; ++j) acc[r][j] = fmaf(a, w[j], acc[r][j]);
            }
        }
        __syncthreads();
        cur ^= 1;
    }

    float bv[10];
    #pragma unroll
    for (int j = 0; j < 10; ++j) bv[j] = bias[lane + 64 * j];
    #pragma unroll
    for (int r = 0; r < 8; ++r)
        #pragma unroll
        for (int j = 0; j < 10; ++j) acc[r][j] += bv[j];

    const float T = *tptr;
    const int vl = vlen[row0 >> 12];

    #pragma unroll
    for (int r = 0; r < 8; ++r) {
        const int row = row0 + wid * 8 + r;
        const int ss = row & (NS - 1);
        const bool valid = ss < vl;

        float z[10];
        #pragma unroll
        for (int j = 0; j < 10; ++j) {
            float u = U[(size_t)row * GC + lane + 64 * j];
            float gn = -logf(-logf(u + EPSV) + EPSV);
            z[j] = (acc[r][j] + gn) / T;
        }

        #pragma unroll
        for (int g = 0; g < 2; ++g) {
            const int j0 = g * 5;
            float mv = z[j0];
            int mo = lane + 64 * j0;
            #pragma unroll
            for (int j = j0 + 1; j < j0 + 5; ++j) {
                if (z[j] > mv) { mv = z[j]; mo = lane + 64 * j; }
            }
            #pragma unroll
            for (int d = 1; d < 64; d <<= 1) {
                float ov = __shfl_xor(mv, d);
                int   oo = __shfl_xor(mo, d);
                if (ov > mv || (ov == mv && oo < mo)) { mv = ov; mo = oo; }
            }
            float se = 0.0f;
            #pragma unroll
            for (int j = j0; j < j0 + 5; ++j) se += expf(z[j] - mv);
            #pragma unroll
            for (int d = 1; d < 64; d <<= 1) se += __shfl_xor(se, d);
            float y = 1.0f / se;
            float q = (1.0f - y) + y;

            float m2 = acc[r][j0];
            #pragma unroll
            for (int j = j0 + 1; j < j0 + 5; ++j) m2 = fmaxf(m2, acc[r][j]);
            #pragma unroll
            for (int d = 1; d < 64; d <<= 1) m2 = fmaxf(m2, __shfl_xor(m2, d));
            float pe[5];
            float s2 = 0.0f;
            #pragma unroll
            for (int jj = 0; jj < 5; ++jj) {
                pe[jj] = expf(acc[r][j0 + jj] - m2);
                s2 += pe[jj];
            }
            #pragma unroll
            for (int d = 1; d < 64; d <<= 1) s2 += __shfl_xor(s2, d);
            if (valid) {
                #pragma unroll
                for (int jj = 0; jj < 5; ++jj)
                    atomicAdd(&uacc[lane + 64 * (j0 + jj)], pe[jj] / s2);
            }

            const int c = mo - g * NC;
            const float2 cv = ((const float2*)(CB + ((size_t)g * NC + c) * DG))[lane];
            float2 ov2;
            ov2.x = q * cv.x;
            ov2.y = q * cv.y;
            ((float2*)(out + (size_t)row * (NG * DG) + g * DG))[lane] = ov2;
        }
    }

    __syncthreads();
    for (int i = t; i < GC; i += 256) atomicAdd(&gacc[i], uacc[i]);
}

extern "C" void kernel_launch(void* const* d_in, const int* in_sizes, int n_in,
                              void* d_out, int out_size, void* d_ws, size_t ws_size,
                              hipStream_t stream)
{
    const float* X    = (const float*)d_in[0];
    const int*   vlen = (const int*)d_in[1];
    const float* U    = (const float*)d_in[2];
    const float* W    = (const float*)d_in[3];
    const float* bias = (const float*)d_in[4];
    const float* CB   = (const float*)d_in[5];
    const float* T    = (const float*)d_in[6];
    float* out = (float*)d_out;

    char* ws = (char*)d_ws;
    // layout (bytes)
    float*     Wt   = (float*)ws;                               // 1,310,720
    float*     gacc = (float*)(ws + 1310720);                   // 2,560
    _Float16*  Whh  = (_Float16*)(ws + 1313792);                // 655,360
    _Float16*  Wll  = (_Float16*)(ws + 1969152);                // 655,360
    _Float16*  Xhh  = (_Float16*)(ws + 2624512);                // 67,108,864
    _Float16*  Xll  = (_Float16*)(ws + 69733376);               // 67,108,864
    float*     lgts = (float*)(ws + 136842240);                 // 167,772,160
    const size_t need = 136842240ull + 167772160ull;            // ~290.6 MB

    hipMemsetAsync(gacc, 0, GC * sizeof(float), stream);

    if (ws_size >= need) {
        const int nx4 = NROW * DIN / 4;   // 8,388,608
        const int nw4 = GC * DIN / 4;     // 81,920
        cvt_split<<<(nx4 + 255) / 256, 256, 0, stream>>>(X, Xhh, Xll, nx4);
        cvt_split<<<(nw4 + 255) / 256, 256, 0, stream>>>(W, Whh, Wll, nw4);
        mfma_logits<<<(NROW / 128) * 5, 256, 0, stream>>>(Xhh, Xll, Whh, Wll, bias, lgts);
        epilogue<<<NROW / RTB, 256, 0, stream>>>(lgts, vlen, U, CB, out, gacc);
    } else {
        transpose_w<<<(GC * DIN + 255) / 256, 256, 0, stream>>>(W, Wt);
        fused_main<<<NROW / RT, 256, 0, stream>>>(X, vlen, U, Wt, bias, CB, T, out, gacc);
    }
    finalize_usage<<<1, GC, 0, stream>>>(gacc, vlen, out + (size_t)NROW * (NG * DG));
}

// Round 8
// 269.024 us; speedup vs baseline: 36.1786x; 1.2376x over previous
//
#include <hip/hip_runtime.h>
#include <math.h>

#define NB 16
#define NS 4096
#define DIN 512
#define NG 2
#define NC 320
#define GC 640          // NG*NC
#define DG 128          // D_out / G
#define NROW (NB*NS)    // 65536
#define EPSV 1e-10f

typedef __attribute__((ext_vector_type(4))) float f32x4;
typedef __attribute__((ext_vector_type(8))) _Float16 f16x8;
typedef __attribute__((ext_vector_type(4))) _Float16 f16x4v;

// async global->LDS, 16B per lane; lds dest is wave-uniform base (+ lane*16 by HW)
__device__ __forceinline__ void gload_lds16(const void* g, void* l) {
    __builtin_amdgcn_global_load_lds(
        (const __attribute__((address_space(1))) void*)g,
        (__attribute__((address_space(3))) void*)l,
        16, 0, 0);
}

// ---------- split f32 -> (f16 hi, f16 lo*2048)  (W only now) ----------
__global__ __launch_bounds__(256) void cvt_split(
    const float* __restrict__ src, _Float16* __restrict__ h,
    _Float16* __restrict__ l, int n4)
{
    int i = blockIdx.x * 256 + threadIdx.x;
    if (i >= n4) return;
    float4 v = ((const float4*)src)[i];
    f16x4v vh, vl;
    float xs[4] = {v.x, v.y, v.z, v.w};
    #pragma unroll
    for (int j = 0; j < 4; ++j) {
        _Float16 hh = (_Float16)xs[j];
        vh[j] = hh;
        vl[j] = (_Float16)((xs[j] - (float)hh) * 2048.0f);
    }
    ((f16x4v*)h)[i] = vh;
    ((f16x4v*)l)[i] = vl;
}

// ---------- MFMA GEMM v2: 512 threads, inline X split, reg-staged A ----------
// logits = Ah*Bh + 2^-11*(Ah*Bl + Al*Bh) + b
__global__ __launch_bounds__(512, 3) void mfma_logits2(
    const float* __restrict__ X,
    const _Float16* __restrict__ Wh, const _Float16* __restrict__ Wl,
    const float* __restrict__ bias, float* __restrict__ logits)
{
    __shared__ _Float16 sA[2][2][128 * 32];   // [buf][h/l], 32 KB
    __shared__ _Float16 sB[2][2][128 * 32];   // 32 KB

    const int t = threadIdx.x;                // 0..511
    const int lane = t & 63;
    const int w = t >> 6;                     // 0..7
    const int wm = w >> 2, wn = w & 3;        // 2M x 4N; per-wave 64x32 (4Mt x 2Nt)

    // grid remap: consecutive nb of one M-panel land on the same XCD
    const int p = blockIdx.x;
    const int o = (p & 7) * 320 + (p >> 3);
    const int mb = o / 5, nb = o - mb * 5;
    const int row0 = mb * 128, n0 = nb * 128;

    // B staging geometry (gload_lds, pre-swizzled source slot)
    const int rl = lane >> 2;                       // row within 16-row chunk
    const int sl = (lane & 3) ^ ((lane >> 3) & 3);  // source k-slot (XOR swizzle)

    auto stageB = [&](int b, int k0) {
        int ro = 16 * w + rl;                       // wave w covers rows 16w..16w+15
        size_t gb = (size_t)(n0 + ro) * DIN + k0 + 8 * sl;
        gload_lds16(Wh + gb, &sB[b][0][w * 512]);
        gload_lds16(Wl + gb, &sB[b][1][w * 512]);
    };

    // A reg-staging: thread t owns (row = t>>2, k-slot q = t&3) of the 128x32 panel
    const int ar = t >> 2, aq = t & 3;
    const int aidx = ar * 32 + 8 * (aq ^ ((ar >> 1) & 3));  // swizzled LDS pos
    const float* aga = X + (size_t)(row0 + ar) * DIN + 8 * aq;

    float4 a0, a1;
    auto loadA = [&](int k0) {
        a0 = ((const float4*)(aga + k0))[0];
        a1 = ((const float4*)(aga + k0))[1];
    };
    auto writeA = [&](int b) {
        float xs[8] = {a0.x, a0.y, a0.z, a0.w, a1.x, a1.y, a1.z, a1.w};
        f16x8 h, l;
        #pragma unroll
        for (int j = 0; j < 8; ++j) {
            _Float16 hh = (_Float16)xs[j];
            h[j] = hh;
            l[j] = (_Float16)((xs[j] - (float)hh) * 2048.0f);
        }
        *(f16x8*)&sA[b][0][aidx] = h;
        *(f16x8*)&sA[b][1][aidx] = l;
    };

    f32x4 accA[4][2], accB[4][2];
    const f32x4 zz = {0.f, 0.f, 0.f, 0.f};
    #pragma unroll
    for (int mt = 0; mt < 4; ++mt)
        #pragma unroll
        for (int nt = 0; nt < 2; ++nt) { accA[mt][nt] = zz; accB[mt][nt] = zz; }

    loadA(0);
    stageB(0, 0);
    writeA(0);
    __syncthreads();

    for (int ks = 0; ks < 16; ++ks) {
        const int cur = ks & 1;
        if (ks < 15) { loadA((ks + 1) * 32); stageB(cur ^ 1, (ks + 1) * 32); }

        f16x8 ah[4], al[4], bh[2], bl[2];
        #pragma unroll
        for (int mt = 0; mt < 4; ++mt) {
            int r = wm * 64 + mt * 16 + (lane & 15);
            int idx = r * 32 + 8 * ((lane >> 4) ^ ((r >> 1) & 3));
            ah[mt] = *(const f16x8*)&sA[cur][0][idx];
            al[mt] = *(const f16x8*)&sA[cur][1][idx];
        }
        #pragma unroll
        for (int nt = 0; nt < 2; ++nt) {
            int r = wn * 32 + nt * 16 + (lane & 15);
            int idx = r * 32 + 8 * ((lane >> 4) ^ ((r >> 1) & 3));
            bh[nt] = *(const f16x8*)&sB[cur][0][idx];
            bl[nt] = *(const f16x8*)&sB[cur][1][idx];
        }
        #pragma unroll
        for (int mt = 0; mt < 4; ++mt)
            #pragma unroll
            for (int nt = 0; nt < 2; ++nt) {
                accA[mt][nt] = __builtin_amdgcn_mfma_f32_16x16x32_f16(ah[mt], bh[nt], accA[mt][nt], 0, 0, 0);
                accB[mt][nt] = __builtin_amdgcn_mfma_f32_16x16x32_f16(ah[mt], bl[nt], accB[mt][nt], 0, 0, 0);
                accB[mt][nt] = __builtin_amdgcn_mfma_f32_16x16x32_f16(al[mt], bh[nt], accB[mt][nt], 0, 0, 0);
            }

        if (ks < 15) writeA(cur ^ 1);   // vmcnt wait lands after compute (T14)
        __syncthreads();
    }

    // combine chains + bias, store f32 logits
    #pragma unroll
    for (int nt = 0; nt < 2; ++nt) {
        int col = n0 + wn * 32 + nt * 16 + (lane & 15);
        float bv = bias[col];
        #pragma unroll
        for (int mt = 0; mt < 4; ++mt) {
            #pragma unroll
            for (int q = 0; q < 4; ++q) {
                int row = row0 + wm * 64 + mt * 16 + (lane >> 4) * 4 + q;
                logits[(size_t)row * GC + col] =
                    accA[mt][nt][q] + accB[mt][nt][q] * (1.0f / 2048.0f) + bv;
            }
        }
    }
}

// ---------- epilogue: ballot-argmax, unstabilized usage softmax (r7-proven) ----------
#define RTB 32
__global__ __launch_bounds__(256, 8) void epilogue(
    const float* __restrict__ logits, const int* __restrict__ vlen,
    const float* __restrict__ U, const float* __restrict__ CB,
    float* __restrict__ out, float* __restrict__ gacc)
{
    __shared__ float uacc[GC];
    const int t = threadIdx.x;
    const int lane = t & 63;
    const int wid = t >> 6;
    const int row0 = blockIdx.x * RTB;

    for (int i = t; i < GC; i += 256) uacc[i] = 0.0f;
    __syncthreads();

    const int vl = vlen[row0 >> 12];

    float ureg[10];
    #pragma unroll
    for (int j = 0; j < 10; ++j) ureg[j] = 0.0f;

    #pragma unroll
    for (int r = 0; r < 8; ++r) {
        const int row = row0 + wid * 8 + r;
        const bool valid = (row & (NS - 1)) < vl;

        float lg[10], zz[10];
        #pragma unroll
        for (int j = 0; j < 10; ++j)
            lg[j] = logits[(size_t)row * GC + lane + 64 * j];
        #pragma unroll
        for (int j = 0; j < 10; ++j) {
            float u = U[(size_t)row * GC + lane + 64 * j];
            zz[j] = lg[j] - logf(-logf(u + EPSV) + EPSV);   // precise: argmax-critical
        }

        #pragma unroll
        for (int g = 0; g < 2; ++g) {
            const int j0 = g * 5;

            // exact max over 320 (value-only butterfly)
            float mv = zz[j0];
            #pragma unroll
            for (int j = j0 + 1; j < j0 + 5; ++j) mv = fmaxf(mv, zz[j]);
            #pragma unroll
            for (int d = 1; d < 64; d <<= 1) mv = fmaxf(mv, __shfl_xor(mv, d));

            // first-occurrence argmax via ballots (idx = lane + 64*j)
            int c = 0;
            #pragma unroll
            for (int jj = 4; jj >= 0; --jj) {
                unsigned long long b = __ballot(zz[j0 + jj] == mv);
                if (b) c = (__ffsll(b) - 1) + 64 * jj;
            }

            // usage softmax, stabilizer-free (logits O(1); shift-invariant)
            float pe[5], s2 = 0.0f;
            #pragma unroll
            for (int jj = 0; jj < 5; ++jj) {
                pe[jj] = __expf(lg[j0 + jj]);
                s2 += pe[jj];
            }
            #pragma unroll
            for (int d = 1; d < 64; d <<= 1) s2 += __shfl_xor(s2, d);
            if (valid) {
                const float inv = 1.0f / s2;
                #pragma unroll
                for (int jj = 0; jj < 5; ++jj) ureg[j0 + jj] += pe[jj] * inv;
            }

            // straight-through output == selected codebook row exactly (q == 1.0)
            const float2 cv = ((const float2*)(CB + ((size_t)g * NC + c) * DG))[lane];
            ((float2*)(out + (size_t)row * (NG * DG) + g * DG))[lane] = cv;
        }
    }

    #pragma unroll
    for (int j = 0; j < 10; ++j)
        atomicAdd(&uacc[lane + 64 * j], ureg[j]);

    __syncthreads();
    for (int i = t; i < GC; i += 256) atomicAdd(&gacc[i], uacc[i]);
}

__global__ void finalize_usage(const float* __restrict__ gacc,
                               const int* __restrict__ vlen,
                               float* __restrict__ usage_out)
{
    int total = 0;
    #pragma unroll
    for (int b = 0; b < NB; ++b) total += vlen[b];
    int o = threadIdx.x;
    if (o < GC) usage_out[o] = gacc[o] / (float)total;
}

// ---------- fallback path (round-4, f32 VALU, proven 928 us) ----------
#define RT 32
#define KC 8
#define NIT (DIN/KC)

__global__ void transpose_w(const float* __restrict__ W, float* __restrict__ Wt) {
    int idx = blockIdx.x * 256 + threadIdx.x;
    if (idx >= GC * DIN) return;
    int k = idx / GC, o = idx - k * GC;
    Wt[idx] = W[(size_t)o * DIN + k];
}

__global__ __launch_bounds__(256, 2) void fused_main(
    const float* __restrict__ X, const int* __restrict__ vlen,
    const float* __restrict__ U, const float* __restrict__ Wt,
    const float* __restrict__ bias, const float* __restrict__ CB,
    const float* __restrict__ tptr, float* __restrict__ out,
    float* __restrict__ gacc)
{
    __shared__ __align__(16) float WtC[2][KC][GC];
    __shared__ __align__(16) float AC[2][RT][KC];
    __shared__ float uacc[GC];

    const int t = threadIdx.x;
    const int lane = t & 63;
    const int wid = t >> 6;
    const int row0 = blockIdx.x * RT;

    for (int i = t; i < GC; i += 256) uacc[i] = 0.0f;

    float acc[8][10];
    #pragma unroll
    for (int r = 0; r < 8; ++r)
        #pragma unroll
        for (int j = 0; j < 10; ++j) acc[r][j] = 0.0f;

    auto stage = [&](int b, int k0) {
        const float* gw = Wt + (size_t)k0 * GC;
        #pragma unroll
        for (int i = 0; i < 5; ++i) {
            int base = (wid * 5 + i) * 256;
            gload_lds16(gw + base + 4 * lane, &WtC[b][0][0] + base);
        }
        if (wid == 0) {
            const float* gx = X + (size_t)(row0 + (lane >> 1)) * DIN + k0 + 4 * (lane & 1);
            gload_lds16(gx, &AC[b][0][0]);
        }
    };

    stage(0, 0);
    __syncthreads();

    int cur = 0;
    for (int it = 0; it < NIT; ++it) {
        if (it + 1 < NIT) stage(cur ^ 1, (it + 1) * KC);
        #pragma unroll
        for (int kk = 0; kk < KC; ++kk) {
            float w[10];
            #pragma unroll
            for (int j = 0; j < 10; ++j) w[j] = WtC[cur][kk][lane + 64 * j];
            #pragma unroll
            for (int r = 0; r < 8; ++r) {
                float a = AC[cur][wid * 8 + r][kk];
                #pragma unroll
                for (int j = 0; j < 10; ++j) acc[r][j] = fmaf(a, w[j], acc[r][j]);
            }
        }
        __syncthreads();
        cur ^= 1;
    }

    float bv[10];
    #pragma unroll
    for (int j = 0; j < 10; ++j) bv[j] = bias[lane + 64 * j];
    #pragma unroll
    for (int r = 0; r < 8; ++r)
        #pragma unroll
        for (int j = 0; j < 10; ++j) acc[r][j] += bv[j];

    const float T = *tptr;
    const int vl = vlen[row0 >> 12];

    #pragma unroll
    for (int r = 0; r < 8; ++r) {
        const int row = row0 + wid * 8 + r;
        const int ss = row & (NS - 1);
        const bool valid = ss < vl;

        float z[10];
        #pragma unroll
        for (int j = 0; j < 10; ++j) {
            float u = U[(size_t)row * GC + lane + 64 * j];
            float gn = -logf(-logf(u + EPSV) + EPSV);
            z[j] = (acc[r][j] + gn) / T;
        }

        #pragma unroll
        for (int g = 0; g < 2; ++g) {
            const int j0 = g * 5;
            float mv = z[j0];
            int mo = lane + 64 * j0;
            #pragma unroll
            for (int j = j0 + 1; j < j0 + 5; ++j) {
                if (z[j] > mv) { mv = z[j]; mo = lane + 64 * j; }
            }
            #pragma unroll
            for (int d = 1; d < 64; d <<= 1) {
                float ov = __shfl_xor(mv, d);
                int   oo = __shfl_xor(mo, d);
                if (ov > mv || (ov == mv && oo < mo)) { mv = ov; mo = oo; }
            }
            float se = 0.0f;
            #pragma unroll
            for (int j = j0; j < j0 + 5; ++j) se += expf(z[j] - mv);
            #pragma unroll
            for (int d = 1; d < 64; d <<= 1) se += __shfl_xor(se, d);
            float y = 1.0f / se;
            float q = (1.0f - y) + y;

            float m2 = acc[r][j0];
            #pragma unroll
            for (int j = j0 + 1; j < j0 + 5; ++j) m2 = fmaxf(m2, acc[r][j]);
            #pragma unroll
            for (int d = 1; d < 64; d <<= 1) m2 = fmaxf(m2, __shfl_xor(m2, d));
            float pe[5];
            float s2 = 0.0f;
            #pragma unroll
            for (int jj = 0; jj < 5; ++jj) {
                pe[jj] = expf(acc[r][j0 + jj] - m2);
                s2 += pe[jj];
            }
            #pragma unroll
            for (int d = 1; d < 64; d <<= 1) s2 += __shfl_xor(s2, d);
            if (valid) {
                #pragma unroll
                for (int jj = 0; jj < 5; ++jj)
                    atomicAdd(&uacc[lane + 64 * (j0 + jj)], pe[jj] / s2);
            }

            const int c = mo - g * NC;
            const float2 cv = ((const float2*)(CB + ((size_t)g * NC + c) * DG))[lane];
            float2 ov2;
            ov2.x = q * cv.x;
            ov2.y = q * cv.y;
            ((float2*)(out + (size_t)row * (NG * DG) + g * DG))[lane] = ov2;
        }
    }

    __syncthreads();
    for (int i = t; i < GC; i += 256) atomicAdd(&gacc[i], uacc[i]);
}

extern "C" void kernel_launch(void* const* d_in, const int* in_sizes, int n_in,
                              void* d_out, int out_size, void* d_ws, size_t ws_size,
                              hipStream_t stream)
{
    const float* X    = (const float*)d_in[0];
    const int*   vlen = (const int*)d_in[1];
    const float* U    = (const float*)d_in[2];
    const float* W    = (const float*)d_in[3];
    const float* bias = (const float*)d_in[4];
    const float* CB   = (const float*)d_in[5];
    const float* T    = (const float*)d_in[6];
    float* out = (float*)d_out;

    char* ws = (char*)d_ws;
    // layout (bytes)
    float*     gacc = (float*)ws;                               // 2,560
    _Float16*  Whh  = (_Float16*)(ws + 4096);                   // 655,360
    _Float16*  Wll  = (_Float16*)(ws + 659456);                 // 655,360
    float*     lgts = (float*)(ws + 1314816);                   // 167,772,160
    float*     Wt   = (float*)(ws + 4096);                      // fallback only (1,310,720)
    const size_t need = 1314816ull + 167772160ull;              // ~169 MB

    hipMemsetAsync(gacc, 0, GC * sizeof(float), stream);

    if (ws_size >= need) {
        const int nw4 = GC * DIN / 4;     // 81,920
        cvt_split<<<(nw4 + 255) / 256, 256, 0, stream>>>(W, Whh, Wll, nw4);
        mfma_logits2<<<(NROW / 128) * 5, 512, 0, stream>>>(X, Whh, Wll, bias, lgts);
        epilogue<<<NROW / RTB, 256, 0, stream>>>(lgts, vlen, U, CB, out, gacc);
    } else {
        transpose_w<<<(GC * DIN + 255) / 256, 256, 0, stream>>>(W, Wt);
        fused_main<<<NROW / RT, 256, 0, stream>>>(X, vlen, U, Wt, bias, CB, T, out, gacc);
    }
    finalize_usage<<<1, GC, 0, stream>>>(gacc, vlen, out + (size_t)NROW * (NG * DG));
}